// Round 11
// baseline (2436.640 us; speedup 1.0000x reference)
//
#include <hip/hip_runtime.h>

typedef __attribute__((ext_vector_type(8))) short short8;
typedef __attribute__((ext_vector_type(4))) float f32x4;
typedef __attribute__((ext_vector_type(4))) unsigned int u32x4;

#define DEV static __device__ __forceinline__

DEV unsigned short f2bf(float f){
  unsigned int u = __float_as_uint(f);
  u += 0x7FFFu + ((u >> 16) & 1u);
  return (unsigned short)(u >> 16);
}
DEV float bf2f(unsigned short h){ return __uint_as_float(((unsigned int)h) << 16); }

DEV f32x4 ntload4(const float* p){ return __builtin_nontemporal_load((const f32x4*)p); }
DEV void ntstore4(float* p, f32x4 v){ __builtin_nontemporal_store(v, (f32x4*)p); }

#define DTM 0.1f   /* DT*TAU_MEM_INV */
#define SYN 0.8f   /* 1 - DT*TAU_SYN_INV */
#define VTH 0.2f

// ---------------------------------------------------------------------------
// prep: weights -> MFMA-fragment-major bf16 hi/mid/lo digit layout:
//   dst[((sg*4 + kg)*COUT + co)*8 + j] = digit(w[co][ci][tap])
// Wave B-fragment load = 16 lanes x contiguous 16B (L2-friendly).
// ---------------------------------------------------------------------------
__global__ __launch_bounds__(256) void prep_kernel(
    const float* __restrict__ w2, const float* __restrict__ w3, const float* __restrict__ w4,
    unsigned short* __restrict__ wb2h, unsigned short* __restrict__ wb2m, unsigned short* __restrict__ wb2l,
    unsigned short* __restrict__ wb3h, unsigned short* __restrict__ wb3m, unsigned short* __restrict__ wb3l,
    unsigned short* __restrict__ wb4h, unsigned short* __restrict__ wb4m, unsigned short* __restrict__ wb4l)
{
  const int N2 = 9*128*64, N3 = 9*256*128, N4 = 9*256*256;
  int tid = blockIdx.x*256 + threadIdx.x;
  if (tid < N2) {           // conv2: CIN=64, CPH=1, stages sg in [0,18)
    int j = tid & 7, co = (tid >> 3) & 127, q = (tid >> 3) >> 7;
    int kg = q & 3, sg = q >> 2;
    int tap = sg >> 1, ks = sg & 1;
    int ci = ks*32 + kg*8 + j;
    float w = w2[(co*64 + ci)*9 + tap];
    unsigned short h = f2bf(w);   float r1 = w - bf2f(h);
    unsigned short m = f2bf(r1);  float r2 = r1 - bf2f(m);
    wb2h[tid] = h; wb2m[tid] = m; wb2l[tid] = f2bf(r2);
    return;
  }
  tid -= N2;
  if (tid < N3) {           // conv3: CIN=128, CPH=2, sg in [0,36)
    int j = tid & 7, co = (tid >> 3) & 255, q = (tid >> 3) >> 8;
    int kg = q & 3, sg = q >> 2;
    int p = sg >> 1, ks = sg & 1, tap = p >> 1, cs = p & 1;
    int ci = cs*64 + ks*32 + kg*8 + j;
    float w = w3[(co*128 + ci)*9 + tap];
    unsigned short h = f2bf(w);   float r1 = w - bf2f(h);
    unsigned short m = f2bf(r1);  float r2 = r1 - bf2f(m);
    wb3h[tid] = h; wb3m[tid] = m; wb3l[tid] = f2bf(r2);
    return;
  }
  tid -= N3;
  if (tid < N4) {           // conv4: CIN=256 as 2 halves of 128, sg in [0,72)
    int j = tid & 7, co = (tid >> 3) & 255, q = (tid >> 3) >> 8;
    int kg = q & 3, sg = q >> 2;
    int hh = sg / 36, sl = sg % 36;
    int p = sl >> 1, ks = sl & 1, tap = p >> 1, cs = p & 1;
    int ci = hh*128 + cs*64 + ks*32 + kg*8 + j;
    float w = w4[(co*256 + ci)*9 + tap];
    unsigned short h = f2bf(w);   float r1 = w - bf2f(h);
    unsigned short m = f2bf(r1);  float r2 = r1 - bf2f(m);
    wb4h[tid] = h; wb4m[tid] = m; wb4l[tid] = f2bf(r2);
  }
}

// ---------------------------------------------------------------------------
// K1: conv1 (fp32 direct, 3->64, 3x3 SAME) + LIF1. grid 512 = 32 imgs x 16 row-pairs
// ---------------------------------------------------------------------------
__global__ __launch_bounds__(256) void k1_conv1_lif(
    const float* __restrict__ x, const float* __restrict__ w1,
    float* __restrict__ v1, float* __restrict__ i1,
    unsigned short* __restrict__ z1, int t)
{
  __shared__ float xs[3][4][34];
  __shared__ float wl[27][64];
  int tid = threadIdx.x;
  int b = blockIdx.x >> 4, y0 = (blockIdx.x & 15) * 2;
  for (int e = tid; e < 3*4*34; e += 256) {
    int ci = e/136, r2 = e%136, r = r2/34, xi = r2%34;
    int y = y0 - 1 + r, xg = xi - 1;
    float v = 0.f;
    if (y >= 0 && y < 32 && xg >= 0 && xg < 32)
      v = x[((t*32 + b)*3 + ci)*1024 + y*32 + xg];
    xs[ci][r][xi] = v;
  }
  for (int e = tid; e < 27*64; e += 256) {
    int row = e >> 6, co = e & 63;
    int ci = row % 3, tap = row / 3, ky = tap/3, kx = tap%3;
    wl[row][co] = w1[((co*3+ci)*3+ky)*3+kx];
  }
  __syncthreads();
  int px = tid >> 2, cg = tid & 3;
  int ly = px >> 5, lx = px & 31;
  float acc[16];
#pragma unroll
  for (int q = 0; q < 16; q++) acc[q] = 0.f;
#pragma unroll
  for (int ky = 0; ky < 3; ky++)
#pragma unroll
    for (int kx = 0; kx < 3; kx++)
#pragma unroll
      for (int ci = 0; ci < 3; ci++) {
        float xv = xs[ci][ly+ky][lx+kx];
        const float4* wr = (const float4*)&wl[(ky*3+kx)*3+ci][cg*16];
#pragma unroll
        for (int q = 0; q < 4; q++) {
          float4 w4 = wr[q];
          acc[q*4+0] = fmaf(xv, w4.x, acc[q*4+0]);
          acc[q*4+1] = fmaf(xv, w4.y, acc[q*4+1]);
          acc[q*4+2] = fmaf(xv, w4.z, acc[q*4+2]);
          acc[q*4+3] = fmaf(xv, w4.w, acc[q*4+3]);
        }
      }
  int m_g = b*1024 + (y0+ly)*32 + lx;
  unsigned short zb[16];
#pragma unroll
  for (int q = 0; q < 4; q++) {
    int idx = m_g*64 + cg*16 + q*4;
    float vv[4] = {0.f,0.f,0.f,0.f}, ii[4] = {0.f,0.f,0.f,0.f};
    if (t != 0) {
      float4 v4 = *(const float4*)(v1+idx); float4 i4 = *(const float4*)(i1+idx);
      vv[0]=v4.x; vv[1]=v4.y; vv[2]=v4.z; vv[3]=v4.w;
      ii[0]=i4.x; ii[1]=i4.y; ii[2]=i4.z; ii[3]=i4.w;
    }
#pragma unroll
    for (int s = 0; s < 4; s++) {
      float vdec = vv[s] + DTM*((0.0f - vv[s]) + ii[s]);
      bool z = (vdec - VTH) > 0.0f;
      vv[s] = z ? 0.0f : vdec;
      ii[s] = SYN*ii[s] + acc[q*4+s];
      zb[q*4+s] = z ? 0x3F80 : 0;
    }
    *(float4*)(v1+idx) = make_float4(vv[0],vv[1],vv[2],vv[3]);
    *(float4*)(i1+idx) = make_float4(ii[0],ii[1],ii[2],ii[3]);
  }
  u32x4 za, zc;
  za[0]=zb[0]|((unsigned)zb[1]<<16); za[1]=zb[2]|((unsigned)zb[3]<<16);
  za[2]=zb[4]|((unsigned)zb[5]<<16); za[3]=zb[6]|((unsigned)zb[7]<<16);
  zc[0]=zb[8]|((unsigned)zb[9]<<16); zc[1]=zb[10]|((unsigned)zb[11]<<16);
  zc[2]=zb[12]|((unsigned)zb[13]<<16); zc[3]=zb[14]|((unsigned)zb[15]<<16);
  *(u32x4*)(z1 + m_g*64 + cg*16) = za;
  *(u32x4*)(z1 + m_g*64 + cg*16 + 8) = zc;
}

// ---------------------------------------------------------------------------
// Implicit-GEMM conv (3x3 SAME) over binary spikes, bf16 hi/mid/lo 3-digit
// MFMA. A staged once in LDS ([ch-group][slot], odd-quad stride). B fragments
// per-lane from fragment-major global (L2-resident), cur/next register double
// buffer, ROLLED loop (small I$ body), no barriers in loop. HALVES=2 runs two
// sequential half-K loops with separate accumulators summed once at the end
// (bit-identical to the old 2-way atomic partial sum). Epilogue: LDS C
// re-tile -> coalesced nontemporal float4 LIF state I/O; POOLZ: fused 2x2
// spike max-pool (binary max == OR).
// ---------------------------------------------------------------------------
template<int MF, int CIN_A, int HALVES, int WI, int HIM, int COUT, int CIN_SRC,
         int NT, bool POOLZ>
__global__ __launch_bounds__(256, 4) void conv_lif(
    const unsigned short* __restrict__ zsrc,
    const unsigned short* __restrict__ wbh, const unsigned short* __restrict__ wbm,
    const unsigned short* __restrict__ wbl,
    float* __restrict__ vst, float* __restrict__ ist,
    unsigned short* __restrict__ zpool, int t)
{
  constexpr int THREADS = 256;
  constexpr int BM = MF*16;
  constexpr int BN = 64;
  constexpr int ROWS = BM/WI;
  constexpr int SLOTW = WI+2;
  constexpr int SLOTS = (ROWS+2)*SLOTW;
  constexpr int KHALF = CIN_A/HALVES;
  constexpr int CPH = KHALF/64;          // 64-ch chunks per half-tap
  constexpr int NSC = 9*CPH;             // loop iterations per half (2 stages each)
  constexpr int MT_PER_B = (HIM*WI)/BM;
  constexpr int ACH = CIN_A/8;           // 8-channel groups staged
  constexpr int ACHUNKS = SLOTS*ACH;
  constexpr int GSTRIDE = (SLOTS+1)*16;  // bytes per ch-group (odd 16B-quad stride)
  constexpr int ABYTES = ACH*GSTRIDE;
  constexpr int CBYTES = BM*BN*4;
  constexpr int ZBYTES = POOLZ ? BM*BN*2 : 0;
  constexpr int EBYTES = CBYTES + ZBYTES;
  constexpr int LDSB = ABYTES > EBYTES ? ABYTES : EBYTES;
  static_assert(LDSB <= 32*1024, "LDS");

  __shared__ __align__(16) char smem[LDSB];

  int tid = threadIdx.x;
  int rem = blockIdx.x;
  int nt = 0;
  if constexpr (NT > 1) { nt = rem % NT; rem /= NT; }
  int b = rem / MT_PER_B;
  int y0 = (rem % MT_PER_B) * ROWS;
  int lane = tid & 63, wn = tid >> 6;
  int kg = lane >> 4;

  // ---- stage A tile (once): [g][slot] LDS layout ----
  for (int ch = tid; ch < ACHUNKS; ch += THREADS) {
    int slot = ch / ACH, g = ch % ACH;
    int yr = slot / SLOTW, xr = slot % SLOTW;
    int y = y0 + yr - 1, xg = xr - 1;
    u32x4 val; val[0]=0; val[1]=0; val[2]=0; val[3]=0;
    if (y >= 0 && y < HIM && xg >= 0 && xg < WI)
      val = *(const u32x4*)(zsrc + ((long)(b*HIM + y)*WI + xg)*CIN_SRC + g*8);
    *(u32x4*)(smem + g*GSTRIDE + slot*16) = val;
  }

  // ---- A-read bases: addr = abase[mf] + uniform(stage) ----
  int abase[MF];
#pragma unroll
  for (int mf = 0; mf < MF; mf++) {
    int pl = mf*16 + (lane & 15);
    int yl = pl / WI, xl = pl % WI;
    abase[mf] = kg*GSTRIDE + (yl*SLOTW + xl)*16;
  }

  int co_g = nt*BN + wn*16 + (lane & 15);
  const long bstep = (long)4*COUT*8;     // elements per K=32 stage
  const long blane = ((long)kg*COUT + co_g)*8;

  f32x4 accsum[MF];
#pragma unroll
  for (int mf = 0; mf < MF; mf++) {
    accsum[mf][0]=0.f; accsum[mf][1]=0.f; accsum[mf][2]=0.f; accsum[mf][3]=0.f;
  }

  __syncthreads();

#pragma unroll
  for (int hh = 0; hh < HALVES; hh++) {
    f32x4 acc[MF];
#pragma unroll
    for (int mf = 0; mf < MF; mf++) {
      acc[mf][0]=0.f; acc[mf][1]=0.f; acc[mf][2]=0.f; acc[mf][3]=0.f;
    }
    long bo = blane + (long)(hh*NSC*2)*bstep;
    short8 ch0 = *(const short8*)(wbh + bo);
    short8 cm0 = *(const short8*)(wbm + bo);
    short8 cl0 = *(const short8*)(wbl + bo);
    short8 ch1 = *(const short8*)(wbh + bo + bstep);
    short8 cm1 = *(const short8*)(wbm + bo + bstep);
    short8 cl1 = *(const short8*)(wbl + bo + bstep);

#pragma unroll 1
    for (int sc = 0; sc < NSC; sc++) {
      long bon = bo + ((sc + 1 < NSC) ? 2*bstep : 0);
      short8 nh0 = *(const short8*)(wbh + bon);
      short8 nm0 = *(const short8*)(wbm + bon);
      short8 nl0 = *(const short8*)(wbl + bon);
      short8 nh1 = *(const short8*)(wbh + bon + bstep);
      short8 nm1 = *(const short8*)(wbm + bon + bstep);
      short8 nl1 = *(const short8*)(wbl + bon + bstep);

      int tap, cs;
      if constexpr (CPH == 1) { tap = sc; cs = 0; }
      else { tap = sc >> 1; cs = sc & 1; }
      int ty = (tap*171) >> 9;           // tap/3
      int tx = tap - ty*3;               // tap%3
      int base0 = (hh*(KHALF/8) + cs*8)*GSTRIDE + (ty*SLOTW + tx)*16;

      short8 a0[MF], a1[MF];
#pragma unroll
      for (int mf = 0; mf < MF; mf++)
        a0[mf] = *(const short8*)(smem + abase[mf] + base0);
#pragma unroll
      for (int mf = 0; mf < MF; mf++)
        a1[mf] = *(const short8*)(smem + abase[mf] + base0 + 4*GSTRIDE);

#pragma unroll
      for (int mf = 0; mf < MF; mf++)
        acc[mf] = __builtin_amdgcn_mfma_f32_16x16x32_bf16(a0[mf], ch0, acc[mf], 0, 0, 0);
#pragma unroll
      for (int mf = 0; mf < MF; mf++)
        acc[mf] = __builtin_amdgcn_mfma_f32_16x16x32_bf16(a0[mf], cm0, acc[mf], 0, 0, 0);
#pragma unroll
      for (int mf = 0; mf < MF; mf++)
        acc[mf] = __builtin_amdgcn_mfma_f32_16x16x32_bf16(a0[mf], cl0, acc[mf], 0, 0, 0);
#pragma unroll
      for (int mf = 0; mf < MF; mf++)
        acc[mf] = __builtin_amdgcn_mfma_f32_16x16x32_bf16(a1[mf], ch1, acc[mf], 0, 0, 0);
#pragma unroll
      for (int mf = 0; mf < MF; mf++)
        acc[mf] = __builtin_amdgcn_mfma_f32_16x16x32_bf16(a1[mf], cm1, acc[mf], 0, 0, 0);
#pragma unroll
      for (int mf = 0; mf < MF; mf++)
        acc[mf] = __builtin_amdgcn_mfma_f32_16x16x32_bf16(a1[mf], cl1, acc[mf], 0, 0, 0);

      ch0 = nh0; cm0 = nm0; cl0 = nl0;
      ch1 = nh1; cm1 = nm1; cl1 = nl1;
      bo = bon;
    }

    if constexpr (HALVES == 1) {
#pragma unroll
      for (int mf = 0; mf < MF; mf++) accsum[mf] = acc[mf];
    } else {
#pragma unroll
      for (int mf = 0; mf < MF; mf++)
#pragma unroll
        for (int r = 0; r < 4; r++) accsum[mf][r] += acc[mf][r];
    }
  }

  // ---- epilogue: re-tile C via LDS -> coalesced float4 LIF state I/O ----
  __syncthreads();                       // A-LDS dead; reuse
  float* cb = (float*)smem;              // [BM][BN] fp32, XOR-swizzled
  unsigned short* zb = (unsigned short*)(smem + CBYTES);  // [BM][BN] u16
  {
    int chn = wn*16 + (lane & 15);
#pragma unroll
    for (int mf = 0; mf < MF; mf++)
#pragma unroll
      for (int r = 0; r < 4; r++) {
        int pix = mf*16 + (lane >> 4)*4 + r;
        cb[pix*BN + (chn ^ ((pix & 3) << 4))] = accsum[mf][r];
      }
  }
  __syncthreads();
  constexpr int ITER = (BM*BN/4)/THREADS;
  int mbase = (b*HIM + y0)*WI;
#pragma unroll
  for (int k = 0; k < ITER; k++) {
    int e = k*THREADS + tid;
    int row = e >> 4;                    // BN/4 = 16 float4 per row
    int ch  = (e & 15) << 2;
    f32x4 cv = *(const f32x4*)&cb[row*BN + (ch ^ ((row & 3) << 4))];
    long gidx = (long)(mbase + row)*COUT + nt*BN + ch;
    f32x4 vv = {0.f,0.f,0.f,0.f}, ii = {0.f,0.f,0.f,0.f};
    if (t != 0) { vv = ntload4(vst + gidx); ii = ntload4(ist + gidx); }
    unsigned short zs[4];
#pragma unroll
    for (int s = 0; s < 4; s++) {
      float vdec = vv[s] + DTM*((0.0f - vv[s]) + ii[s]);
      bool z = (vdec - VTH) > 0.0f;
      vv[s] = z ? 0.0f : vdec;
      ii[s] = SYN*ii[s] + cv[s];
      zs[s] = z ? 0x3F80 : 0;
    }
    ntstore4(vst + gidx, vv);
    ntstore4(ist + gidx, ii);
    if constexpr (POOLZ)
      *(ushort4*)&zb[row*BN + ch] = make_ushort4(zs[0],zs[1],zs[2],zs[3]);
  }

  // ---- fused 2x2 max-pool of spikes (binary max == OR), coalesced write ----
  if constexpr (POOLZ) {
    __syncthreads();
    constexpr int WP = WI/2, PR = ROWS/2, CH16 = BN/8;
    for (int c = tid; c < PR*WP*CH16; c += THREADS) {
      int ppx = c / CH16, ck = c % CH16;
      int py = ppx / WP, px = ppx % WP;
      int b0_ = ((2*py)*WI + 2*px)*BN + ck*8;
      u32x4 q0 = *(const u32x4*)(zb + b0_);
      u32x4 q1 = *(const u32x4*)(zb + b0_ + BN);
      u32x4 q2 = *(const u32x4*)(zb + b0_ + WI*BN);
      u32x4 q3 = *(const u32x4*)(zb + b0_ + WI*BN + BN);
      u32x4 vo = (q0|q1)|(q2|q3);
      long g = ((long)(b*(HIM/2) + (y0>>1) + py)*WP + px)*COUT + nt*BN + ck*8;
      *(u32x4*)(zpool + g) = vo;
    }
  }
}

// ---------------------------------------------------------------------------
// K5: FC(4096->10) over pooled spikes + LI + noise + running max.
// 512 threads, one block per image. Unconditional fmaf (z in {0,1}).
// ---------------------------------------------------------------------------
__global__ __launch_bounds__(512) void k5_fc(
    const unsigned short* __restrict__ z4p, const float* __restrict__ wfc,
    const float* __restrict__ noise,
    float* __restrict__ vl, float* __restrict__ il, float* __restrict__ dout, int t)
{
  __shared__ float red[8][10];
  int tid = threadIdx.x, b = blockIdx.x;
  float sums[10];
#pragma unroll
  for (int j = 0; j < 10; j++) sums[j] = 0.f;
#pragma unroll
  for (int q = 0; q < 8; q++) {
    int k = q*512 + tid;
    int c = k >> 4, s = k & 15, py = s >> 2, px = s & 3;
    float zf = bf2f(z4p[((b*4 + py)*4 + px)*256 + c]);
#pragma unroll
    for (int j = 0; j < 10; j++)
      sums[j] = fmaf(zf, wfc[j*4096 + k], sums[j]);
  }
#pragma unroll
  for (int j = 0; j < 10; j++) {
    float v = sums[j];
    for (int off = 32; off; off >>= 1) v += __shfl_xor(v, off);
    if ((tid & 63) == 0) red[tid >> 6][j] = v;
  }
  __syncthreads();
  if (tid < 10) {
    float o = 0.f;
#pragma unroll
    for (int w = 0; w < 8; w++) o += red[w][tid];
    float vo = 0.f, io = 0.f;
    if (t != 0) { vo = vl[b*10 + tid]; io = il[b*10 + tid]; }
    float vn = vo + DTM*((0.0f - vo) + io);
    float inw = SYN*io + o;
    vl[b*10 + tid] = vn; il[b*10 + tid] = inw;
    float volt = vn + 0.001f*noise[((long)t*32 + b)*10 + tid];
    dout[b*10 + tid] = (t == 0) ? volt : fmaxf(dout[b*10 + tid], volt);
  }
}

// ---------------------------------------------------------------------------
extern "C" void kernel_launch(void* const* d_in, const int* in_sizes, int n_in,
                              void* d_out, int out_size, void* d_ws, size_t ws_size,
                              hipStream_t stream)
{
  const float* x     = (const float*)d_in[0];
  const float* noise = (const float*)d_in[1];
  const float* w1    = (const float*)d_in[2];
  const float* w2    = (const float*)d_in[3];
  const float* w3    = (const float*)d_in[4];
  const float* w4    = (const float*)d_in[5];
  const float* wfc   = (const float*)d_in[6];
  float* dout = (float*)d_out;

  char* ws = (char*)d_ws;
  size_t off = 0;
  auto alloc = [&](size_t bytes) -> char* {
    char* p = ws + off;
    off = (off + bytes + 255) & ~(size_t)255;
    return p;
  };
  float* v1 = (float*)alloc(2097152u*4); float* i1 = (float*)alloc(2097152u*4);
  float* v2 = (float*)alloc(4194304u*4); float* i2 = (float*)alloc(4194304u*4);
  float* v3 = (float*)alloc(2097152u*4); float* i3 = (float*)alloc(2097152u*4);
  float* v4 = (float*)alloc(524288u*4);  float* i4 = (float*)alloc(524288u*4);
  unsigned short* z1  = (unsigned short*)alloc(2097152u*2);   // full-res spikes L1
  unsigned short* z2p = (unsigned short*)alloc(1048576u*2);   // pooled L2: [32][16][16][128]
  unsigned short* z3p = (unsigned short*)alloc(524288u*2);    // pooled L3: [32][8][8][256]
  unsigned short* z4p = (unsigned short*)alloc(131072u*2);    // pooled L4: [32][4][4][256]
  float* vl = (float*)alloc(1280);
  float* il = (float*)alloc(1280);
  unsigned short* wb2h = (unsigned short*)alloc(73728u*2);
  unsigned short* wb2m = (unsigned short*)alloc(73728u*2);
  unsigned short* wb2l = (unsigned short*)alloc(73728u*2);
  unsigned short* wb3h = (unsigned short*)alloc(294912u*2);
  unsigned short* wb3m = (unsigned short*)alloc(294912u*2);
  unsigned short* wb3l = (unsigned short*)alloc(294912u*2);
  unsigned short* wb4h = (unsigned short*)alloc(589824u*2);
  unsigned short* wb4m = (unsigned short*)alloc(589824u*2);
  unsigned short* wb4l = (unsigned short*)alloc(589824u*2);

  prep_kernel<<<3744, 256, 0, stream>>>(w2, w3, w4,
      wb2h, wb2m, wb2l, wb3h, wb3m, wb3l, wb4h, wb4m, wb4l);

  for (int t = 0; t < 16; t++) {
    k1_conv1_lif<<<512, 256, 0, stream>>>(x, w1, v1, i1, z1, t);
    // conv2: 64->128 @32x32, BM=64 BN=64 NT=2, grid 1024
    conv_lif<4, 64,1,32,32,128, 64,2,true><<<1024, 256, 0, stream>>>(
        z1, wb2h, wb2m, wb2l, v2, i2, z2p, t);
    // conv3: 128->256 @16x16 pooled-in, BM=32 BN=64 NT=4, grid 1024
    conv_lif<2,128,1,16,16,256,128,4,true><<<1024, 256, 0, stream>>>(
        z2p, wb3h, wb3m, wb3l, v3, i3, z3p, t);
    // conv4: 256->256 @8x8 pooled-in, FULL K in-block (2 halves), grid 256
    conv_lif<2,256,2, 8, 8,256,256,4,true><<<256, 256, 0, stream>>>(
        z3p, wb4h, wb4m, wb4l, v4, i4, z4p, t);
    k5_fc<<<32, 512, 0, stream>>>(z4p, wfc, noise, vl, il, dout, t);
  }
}

// Round 12
// 1918.889 us; speedup vs baseline: 1.2698x; 1.2698x over previous
//
#include <hip/hip_runtime.h>

typedef __attribute__((ext_vector_type(8))) short short8;
typedef __attribute__((ext_vector_type(4))) float f32x4;
typedef __attribute__((ext_vector_type(4))) unsigned int u32x4;

#define DEV static __device__ __forceinline__

DEV unsigned short f2bf(float f){
  unsigned int u = __float_as_uint(f);
  u += 0x7FFFu + ((u >> 16) & 1u);
  return (unsigned short)(u >> 16);
}
DEV float bf2f(unsigned short h){ return __uint_as_float(((unsigned int)h) << 16); }

DEV f32x4 ntload4(const float* p){ return __builtin_nontemporal_load((const f32x4*)p); }
DEV void ntstore4(float* p, f32x4 v){ __builtin_nontemporal_store(v, (f32x4*)p); }

#define DTM 0.1f   /* DT*TAU_MEM_INV */
#define SYN 0.8f   /* 1 - DT*TAU_SYN_INV */
#define VTH 0.2f

// ---------------------------------------------------------------------------
// prep: weights -> MFMA-fragment-major bf16 hi/mid/lo digit layout:
//   dst[((sg*4 + kg)*COUT + co)*8 + j] = digit(w[co][ci][tap])
// Wave B-fragment load = 16 lanes x contiguous 16B (L2-friendly).
// ---------------------------------------------------------------------------
__global__ __launch_bounds__(256) void prep_kernel(
    const float* __restrict__ w2, const float* __restrict__ w3, const float* __restrict__ w4,
    unsigned short* __restrict__ wb2h, unsigned short* __restrict__ wb2m, unsigned short* __restrict__ wb2l,
    unsigned short* __restrict__ wb3h, unsigned short* __restrict__ wb3m, unsigned short* __restrict__ wb3l,
    unsigned short* __restrict__ wb4h, unsigned short* __restrict__ wb4m, unsigned short* __restrict__ wb4l)
{
  const int N2 = 9*128*64, N3 = 9*256*128, N4 = 9*256*256;
  int tid = blockIdx.x*256 + threadIdx.x;
  if (tid < N2) {           // conv2: CIN=64, sg in [0,18)
    int j = tid & 7, co = (tid >> 3) & 127, q = (tid >> 3) >> 7;
    int kg = q & 3, sg = q >> 2;
    int tap = sg >> 1, ks = sg & 1;
    int ci = ks*32 + kg*8 + j;
    float w = w2[(co*64 + ci)*9 + tap];
    unsigned short h = f2bf(w);   float r1 = w - bf2f(h);
    unsigned short m = f2bf(r1);  float r2 = r1 - bf2f(m);
    wb2h[tid] = h; wb2m[tid] = m; wb2l[tid] = f2bf(r2);
    return;
  }
  tid -= N2;
  if (tid < N3) {           // conv3: CIN=128, sg in [0,36)
    int j = tid & 7, co = (tid >> 3) & 255, q = (tid >> 3) >> 8;
    int kg = q & 3, sg = q >> 2;
    int p = sg >> 1, ks = sg & 1, tap = p >> 1, cs = p & 1;
    int ci = cs*64 + ks*32 + kg*8 + j;
    float w = w3[(co*128 + ci)*9 + tap];
    unsigned short h = f2bf(w);   float r1 = w - bf2f(h);
    unsigned short m = f2bf(r1);  float r2 = r1 - bf2f(m);
    wb3h[tid] = h; wb3m[tid] = m; wb3l[tid] = f2bf(r2);
    return;
  }
  tid -= N3;
  if (tid < N4) {           // conv4: CIN=256 as 2 halves of 128, sg in [0,72)
    int j = tid & 7, co = (tid >> 3) & 255, q = (tid >> 3) >> 8;
    int kg = q & 3, sg = q >> 2;
    int hh = sg / 36, sl = sg % 36;
    int p = sl >> 1, ks = sl & 1, tap = p >> 1, cs = p & 1;
    int ci = hh*128 + cs*64 + ks*32 + kg*8 + j;
    float w = w4[(co*256 + ci)*9 + tap];
    unsigned short h = f2bf(w);   float r1 = w - bf2f(h);
    unsigned short m = f2bf(r1);  float r2 = r1 - bf2f(m);
    wb4h[tid] = h; wb4m[tid] = m; wb4l[tid] = f2bf(r2);
  }
}

// ---------------------------------------------------------------------------
// K1: conv1 (fp32 direct, 3->64, 3x3 SAME) + LIF1. grid 512 = 32 imgs x 16 row-pairs
// ---------------------------------------------------------------------------
__global__ __launch_bounds__(256) void k1_conv1_lif(
    const float* __restrict__ x, const float* __restrict__ w1,
    float* __restrict__ v1, float* __restrict__ i1,
    unsigned short* __restrict__ z1, int t)
{
  __shared__ float xs[3][4][34];
  __shared__ float wl[27][64];
  int tid = threadIdx.x;
  int b = blockIdx.x >> 4, y0 = (blockIdx.x & 15) * 2;
  for (int e = tid; e < 3*4*34; e += 256) {
    int ci = e/136, r2 = e%136, r = r2/34, xi = r2%34;
    int y = y0 - 1 + r, xg = xi - 1;
    float v = 0.f;
    if (y >= 0 && y < 32 && xg >= 0 && xg < 32)
      v = x[((t*32 + b)*3 + ci)*1024 + y*32 + xg];
    xs[ci][r][xi] = v;
  }
  for (int e = tid; e < 27*64; e += 256) {
    int row = e >> 6, co = e & 63;
    int ci = row % 3, tap = row / 3, ky = tap/3, kx = tap%3;
    wl[row][co] = w1[((co*3+ci)*3+ky)*3+kx];
  }
  __syncthreads();
  int px = tid >> 2, cg = tid & 3;
  int ly = px >> 5, lx = px & 31;
  float acc[16];
#pragma unroll
  for (int q = 0; q < 16; q++) acc[q] = 0.f;
#pragma unroll
  for (int ky = 0; ky < 3; ky++)
#pragma unroll
    for (int kx = 0; kx < 3; kx++)
#pragma unroll
      for (int ci = 0; ci < 3; ci++) {
        float xv = xs[ci][ly+ky][lx+kx];
        const float4* wr = (const float4*)&wl[(ky*3+kx)*3+ci][cg*16];
#pragma unroll
        for (int q = 0; q < 4; q++) {
          float4 w4 = wr[q];
          acc[q*4+0] = fmaf(xv, w4.x, acc[q*4+0]);
          acc[q*4+1] = fmaf(xv, w4.y, acc[q*4+1]);
          acc[q*4+2] = fmaf(xv, w4.z, acc[q*4+2]);
          acc[q*4+3] = fmaf(xv, w4.w, acc[q*4+3]);
        }
      }
  int m_g = b*1024 + (y0+ly)*32 + lx;
  unsigned short zb[16];
#pragma unroll
  for (int q = 0; q < 4; q++) {
    int idx = m_g*64 + cg*16 + q*4;
    float vv[4] = {0.f,0.f,0.f,0.f}, ii[4] = {0.f,0.f,0.f,0.f};
    if (t != 0) {
      float4 v4 = *(const float4*)(v1+idx); float4 i4 = *(const float4*)(i1+idx);
      vv[0]=v4.x; vv[1]=v4.y; vv[2]=v4.z; vv[3]=v4.w;
      ii[0]=i4.x; ii[1]=i4.y; ii[2]=i4.z; ii[3]=i4.w;
    }
#pragma unroll
    for (int s = 0; s < 4; s++) {
      float vdec = vv[s] + DTM*((0.0f - vv[s]) + ii[s]);
      bool z = (vdec - VTH) > 0.0f;
      vv[s] = z ? 0.0f : vdec;
      ii[s] = SYN*ii[s] + acc[q*4+s];
      zb[q*4+s] = z ? 0x3F80 : 0;
    }
    *(float4*)(v1+idx) = make_float4(vv[0],vv[1],vv[2],vv[3]);
    *(float4*)(i1+idx) = make_float4(ii[0],ii[1],ii[2],ii[3]);
  }
  u32x4 za, zc;
  za[0]=zb[0]|((unsigned)zb[1]<<16); za[1]=zb[2]|((unsigned)zb[3]<<16);
  za[2]=zb[4]|((unsigned)zb[5]<<16); za[3]=zb[6]|((unsigned)zb[7]<<16);
  zc[0]=zb[8]|((unsigned)zb[9]<<16); zc[1]=zb[10]|((unsigned)zb[11]<<16);
  zc[2]=zb[12]|((unsigned)zb[13]<<16); zc[3]=zb[14]|((unsigned)zb[15]<<16);
  *(u32x4*)(z1 + m_g*64 + cg*16) = za;
  *(u32x4*)(z1 + m_g*64 + cg*16 + 8) = zc;
}

// ---------------------------------------------------------------------------
// Implicit-GEMM conv (3x3 SAME) over binary spikes, bf16 hi/mid/lo 3-digit
// MFMA. A staged once in LDS ([ch-group][slot], odd-quad stride). B fragments
// per-lane from fragment-major global (L2-resident), cur/next register double
// buffer, rolled loop, no barriers in loop. KSPLIT: block handles one K-half
// (kh), writes raw partial sums to its OWN buffer (plain stores -- no
// atomics); k5 sums the two halves (same pairing as the full-K version).
// Otherwise: fused LIF epilogue via LDS C re-tile -> coalesced nontemporal
// float4 state I/O; POOLZ: fused 2x2 spike max-pool (binary max == OR).
// ---------------------------------------------------------------------------
template<int MF, int CIN_A, int WI, int HIM, int COUT, int CIN_SRC,
         int NT, bool KSPLIT, bool POOLZ>
__global__ __launch_bounds__(256, 4) void conv_lif(
    const unsigned short* __restrict__ zsrc,
    const unsigned short* __restrict__ wbh, const unsigned short* __restrict__ wbm,
    const unsigned short* __restrict__ wbl,
    float* __restrict__ vst, float* __restrict__ ist,
    unsigned short* __restrict__ zpool,
    float* __restrict__ part0, float* __restrict__ part1, int t)
{
  constexpr int THREADS = 256;
  constexpr int BM = MF*16;
  constexpr int BN = 64;
  constexpr int ROWS = BM/WI;
  constexpr int SLOTW = WI+2;
  constexpr int SLOTS = (ROWS+2)*SLOTW;
  constexpr int CPH = CIN_A/64;          // 64-ch chunks per tap (staged half)
  constexpr int NSC = 9*CPH;             // loop iterations (2 K=32 stages each)
  constexpr int MT_PER_B = (HIM*WI)/BM;
  constexpr int ACH = CIN_A/8;           // 8-channel groups staged
  constexpr int ACHUNKS = SLOTS*ACH;
  constexpr int GSTRIDE = (SLOTS+1)*16;  // bytes per ch-group (odd 16B-quad stride)
  constexpr int ABYTES = ACH*GSTRIDE;
  constexpr int CBYTES = BM*BN*4;
  constexpr int ZBYTES = POOLZ ? BM*BN*2 : 0;
  constexpr int EBYTES = CBYTES + ZBYTES;
  constexpr int LDSB = ABYTES > EBYTES ? ABYTES : EBYTES;
  static_assert(LDSB <= 32*1024, "LDS");

  __shared__ __align__(16) char smem[LDSB];

  int tid = threadIdx.x;
  int rem = blockIdx.x;
  int kh = 0;
  if constexpr (KSPLIT) { kh = rem & 1; rem >>= 1; }
  int nt = 0;
  if constexpr (NT > 1) { nt = rem % NT; rem /= NT; }
  int b = rem / MT_PER_B;
  int y0 = (rem % MT_PER_B) * ROWS;
  int lane = tid & 63, wn = tid >> 6;
  int kg = lane >> 4;
  int csrc0 = KSPLIT ? kh*CIN_A : 0;

  // ---- stage A tile (once): [g][slot] LDS layout ----
  for (int ch = tid; ch < ACHUNKS; ch += THREADS) {
    int slot = ch / ACH, g = ch % ACH;
    int yr = slot / SLOTW, xr = slot % SLOTW;
    int y = y0 + yr - 1, xg = xr - 1;
    u32x4 val; val[0]=0; val[1]=0; val[2]=0; val[3]=0;
    if (y >= 0 && y < HIM && xg >= 0 && xg < WI)
      val = *(const u32x4*)(zsrc + ((long)(b*HIM + y)*WI + xg)*CIN_SRC + csrc0 + g*8);
    *(u32x4*)(smem + g*GSTRIDE + slot*16) = val;
  }

  // ---- A-read bases: addr = abase[mf] + uniform(stage) ----
  int abase[MF];
#pragma unroll
  for (int mf = 0; mf < MF; mf++) {
    int pl = mf*16 + (lane & 15);
    int yl = pl / WI, xl = pl % WI;
    abase[mf] = kg*GSTRIDE + (yl*SLOTW + xl)*16;
  }

  int co_g = nt*BN + wn*16 + (lane & 15);
  const long bstep = (long)4*COUT*8;     // elements per K=32 stage
  long bo = ((long)kg*COUT + co_g)*8 + (KSPLIT ? (long)(kh*NSC*2)*bstep : 0);

  f32x4 acc[MF];
#pragma unroll
  for (int mf = 0; mf < MF; mf++) {
    acc[mf][0]=0.f; acc[mf][1]=0.f; acc[mf][2]=0.f; acc[mf][3]=0.f;
  }

  short8 ch0 = *(const short8*)(wbh + bo);
  short8 cm0 = *(const short8*)(wbm + bo);
  short8 cl0 = *(const short8*)(wbl + bo);
  short8 ch1 = *(const short8*)(wbh + bo + bstep);
  short8 cm1 = *(const short8*)(wbm + bo + bstep);
  short8 cl1 = *(const short8*)(wbl + bo + bstep);

  __syncthreads();

#pragma unroll 1
  for (int sc = 0; sc < NSC; sc++) {
    long bon = bo + ((sc + 1 < NSC) ? 2*bstep : 0);
    short8 nh0 = *(const short8*)(wbh + bon);
    short8 nm0 = *(const short8*)(wbm + bon);
    short8 nl0 = *(const short8*)(wbl + bon);
    short8 nh1 = *(const short8*)(wbh + bon + bstep);
    short8 nm1 = *(const short8*)(wbm + bon + bstep);
    short8 nl1 = *(const short8*)(wbl + bon + bstep);

    int tap, cs;
    if constexpr (CPH == 1) { tap = sc; cs = 0; }
    else { tap = sc >> 1; cs = sc & 1; }
    int ty = (tap*171) >> 9;           // tap/3
    int tx = tap - ty*3;               // tap%3
    int base0 = (cs*8)*GSTRIDE + (ty*SLOTW + tx)*16;

    short8 a0[MF], a1[MF];
#pragma unroll
    for (int mf = 0; mf < MF; mf++)
      a0[mf] = *(const short8*)(smem + abase[mf] + base0);
#pragma unroll
    for (int mf = 0; mf < MF; mf++)
      a1[mf] = *(const short8*)(smem + abase[mf] + base0 + 4*GSTRIDE);

#pragma unroll
    for (int mf = 0; mf < MF; mf++)
      acc[mf] = __builtin_amdgcn_mfma_f32_16x16x32_bf16(a0[mf], ch0, acc[mf], 0, 0, 0);
#pragma unroll
    for (int mf = 0; mf < MF; mf++)
      acc[mf] = __builtin_amdgcn_mfma_f32_16x16x32_bf16(a0[mf], cm0, acc[mf], 0, 0, 0);
#pragma unroll
    for (int mf = 0; mf < MF; mf++)
      acc[mf] = __builtin_amdgcn_mfma_f32_16x16x32_bf16(a0[mf], cl0, acc[mf], 0, 0, 0);
#pragma unroll
    for (int mf = 0; mf < MF; mf++)
      acc[mf] = __builtin_amdgcn_mfma_f32_16x16x32_bf16(a1[mf], ch1, acc[mf], 0, 0, 0);
#pragma unroll
    for (int mf = 0; mf < MF; mf++)
      acc[mf] = __builtin_amdgcn_mfma_f32_16x16x32_bf16(a1[mf], cm1, acc[mf], 0, 0, 0);
#pragma unroll
    for (int mf = 0; mf < MF; mf++)
      acc[mf] = __builtin_amdgcn_mfma_f32_16x16x32_bf16(a1[mf], cl1, acc[mf], 0, 0, 0);

    ch0 = nh0; cm0 = nm0; cl0 = nl0;
    ch1 = nh1; cm1 = nm1; cl1 = nl1;
    bo = bon;
  }

  // ---- epilogue: re-tile C via LDS -> coalesced float4 I/O ----
  __syncthreads();                       // A-LDS dead; reuse
  float* cb = (float*)smem;              // [BM][BN] fp32, XOR-swizzled
  unsigned short* zb = (unsigned short*)(smem + CBYTES);  // [BM][BN] u16
  {
    int chn = wn*16 + (lane & 15);
#pragma unroll
    for (int mf = 0; mf < MF; mf++)
#pragma unroll
      for (int r = 0; r < 4; r++) {
        int pix = mf*16 + (lane >> 4)*4 + r;
        cb[pix*BN + (chn ^ ((pix & 3) << 4))] = acc[mf][r];
      }
  }
  __syncthreads();
  constexpr int ITER = (BM*BN/4)/THREADS;
  int mbase = (b*HIM + y0)*WI;
  float* pdst = KSPLIT ? (kh ? part1 : part0) : nullptr;
#pragma unroll
  for (int k = 0; k < ITER; k++) {
    int e = k*THREADS + tid;
    int row = e >> 4;                    // BN/4 = 16 float4 per row
    int ch  = (e & 15) << 2;
    f32x4 cv = *(const f32x4*)&cb[row*BN + (ch ^ ((row & 3) << 4))];
    long gidx = (long)(mbase + row)*COUT + nt*BN + ch;
    if constexpr (KSPLIT) {
      ntstore4(pdst + gidx, cv);
    } else {
      f32x4 vv = {0.f,0.f,0.f,0.f}, ii = {0.f,0.f,0.f,0.f};
      if (t != 0) { vv = ntload4(vst + gidx); ii = ntload4(ist + gidx); }
      unsigned short zs[4];
#pragma unroll
      for (int s = 0; s < 4; s++) {
        float vdec = vv[s] + DTM*((0.0f - vv[s]) + ii[s]);
        bool z = (vdec - VTH) > 0.0f;
        vv[s] = z ? 0.0f : vdec;
        ii[s] = SYN*ii[s] + cv[s];
        zs[s] = z ? 0x3F80 : 0;
      }
      ntstore4(vst + gidx, vv);
      ntstore4(ist + gidx, ii);
      if constexpr (POOLZ)
        *(ushort4*)&zb[row*BN + ch] = make_ushort4(zs[0],zs[1],zs[2],zs[3]);
    }
  }

  // ---- fused 2x2 max-pool of spikes (binary max == OR), coalesced write ----
  if constexpr (POOLZ) {
    __syncthreads();
    constexpr int WP = WI/2, PR = ROWS/2, CH16 = BN/8;
    for (int c = tid; c < PR*WP*CH16; c += THREADS) {
      int ppx = c / CH16, ck = c % CH16;
      int py = ppx / WP, px = ppx % WP;
      int b0_ = ((2*py)*WI + 2*px)*BN + ck*8;
      u32x4 q0 = *(const u32x4*)(zb + b0_);
      u32x4 q1 = *(const u32x4*)(zb + b0_ + BN);
      u32x4 q2 = *(const u32x4*)(zb + b0_ + WI*BN);
      u32x4 q3 = *(const u32x4*)(zb + b0_ + WI*BN + BN);
      u32x4 vo = (q0|q1)|(q2|q3);
      long g = ((long)(b*(HIM/2) + (y0>>1) + py)*WP + px)*COUT + nt*BN + ck*8;
      *(u32x4*)(zpool + g) = vo;
    }
  }
}

// ---------------------------------------------------------------------------
// K5: sum conv4 half-K partials + LIF4 + 2x2 pool + FC(4096->10) + LI + noise
// + running max. 512 threads, one block per image. No atomics, no zeroing.
// ---------------------------------------------------------------------------
__global__ __launch_bounds__(512) void k5_lif4_fc(
    const float* __restrict__ p0, const float* __restrict__ p1,
    float* __restrict__ v4, float* __restrict__ i4,
    const float* __restrict__ wfc, const float* __restrict__ noise,
    float* __restrict__ vl, float* __restrict__ il, float* __restrict__ dout, int t)
{
  __shared__ unsigned zbits[64][8];
  __shared__ unsigned pb[16][8];
  __shared__ float red[8][10];
  int tid = threadIdx.x, b = blockIdx.x;
  int px = tid >> 3, c8 = tid & 7;      // 64 px x 8 groups of 32 ch
  long base = ((long)b*64 + px)*256 + c8*32;
  unsigned mask = 0u;
#pragma unroll
  for (int q = 0; q < 8; q++) {
    f32x4 pa = ntload4(p0 + base + q*4);
    f32x4 pbv = ntload4(p1 + base + q*4);
    float vv[4] = {0.f,0.f,0.f,0.f}, ii[4] = {0.f,0.f,0.f,0.f};
    if (t != 0) {
      float4 v4v = *(const float4*)(v4 + base + q*4);
      float4 i4v = *(const float4*)(i4 + base + q*4);
      vv[0]=v4v.x; vv[1]=v4v.y; vv[2]=v4v.z; vv[3]=v4v.w;
      ii[0]=i4v.x; ii[1]=i4v.y; ii[2]=i4v.z; ii[3]=i4v.w;
    }
#pragma unroll
    for (int s = 0; s < 4; s++) {
      float cv = pa[s] + pbv[s];
      float vdec = vv[s] + DTM*((0.0f - vv[s]) + ii[s]);
      bool z = (vdec - VTH) > 0.0f;
      vv[s] = z ? 0.0f : vdec;
      ii[s] = SYN*ii[s] + cv;
      if (z) mask |= (1u << (q*4 + s));
    }
    *(float4*)(v4 + base + q*4) = make_float4(vv[0],vv[1],vv[2],vv[3]);
    *(float4*)(i4 + base + q*4) = make_float4(ii[0],ii[1],ii[2],ii[3]);
  }
  zbits[px][c8] = mask;
  __syncthreads();
  if (tid < 128) {
    int pp = tid >> 3, grp = tid & 7;
    int py = pp >> 2, pxx = pp & 3;
    int p00 = (2*py)*8 + 2*pxx;
    pb[pp][grp] = zbits[p00][grp] | zbits[p00+1][grp] | zbits[p00+8][grp] | zbits[p00+9][grp];
  }
  __syncthreads();
  float sums[10];
#pragma unroll
  for (int j = 0; j < 10; j++) sums[j] = 0.f;
#pragma unroll
  for (int q = 0; q < 8; q++) {
    int k = q*512 + tid;
    int c = k >> 4, s = k & 15;
    if ((pb[s][c >> 5] >> (c & 31)) & 1u) {
#pragma unroll
      for (int j = 0; j < 10; j++) sums[j] += wfc[j*4096 + k];
    }
  }
#pragma unroll
  for (int j = 0; j < 10; j++) {
    float v = sums[j];
    for (int off = 32; off; off >>= 1) v += __shfl_xor(v, off);
    if ((tid & 63) == 0) red[tid >> 6][j] = v;
  }
  __syncthreads();
  if (tid < 10) {
    float o = 0.f;
#pragma unroll
    for (int w = 0; w < 8; w++) o += red[w][tid];
    float vo = 0.f, io = 0.f;
    if (t != 0) { vo = vl[b*10 + tid]; io = il[b*10 + tid]; }
    float vn = vo + DTM*((0.0f - vo) + io);
    float inw = SYN*io + o;
    vl[b*10 + tid] = vn; il[b*10 + tid] = inw;
    float volt = vn + 0.001f*noise[((long)t*32 + b)*10 + tid];
    dout[b*10 + tid] = (t == 0) ? volt : fmaxf(dout[b*10 + tid], volt);
  }
}

// ---------------------------------------------------------------------------
extern "C" void kernel_launch(void* const* d_in, const int* in_sizes, int n_in,
                              void* d_out, int out_size, void* d_ws, size_t ws_size,
                              hipStream_t stream)
{
  const float* x     = (const float*)d_in[0];
  const float* noise = (const float*)d_in[1];
  const float* w1    = (const float*)d_in[2];
  const float* w2    = (const float*)d_in[3];
  const float* w3    = (const float*)d_in[4];
  const float* w4    = (const float*)d_in[5];
  const float* wfc   = (const float*)d_in[6];
  float* dout = (float*)d_out;

  char* ws = (char*)d_ws;
  size_t off = 0;
  auto alloc = [&](size_t bytes) -> char* {
    char* p = ws + off;
    off = (off + bytes + 255) & ~(size_t)255;
    return p;
  };
  float* v1 = (float*)alloc(2097152u*4); float* i1 = (float*)alloc(2097152u*4);
  float* v2 = (float*)alloc(4194304u*4); float* i2 = (float*)alloc(4194304u*4);
  float* v3 = (float*)alloc(2097152u*4); float* i3 = (float*)alloc(2097152u*4);
  float* v4 = (float*)alloc(524288u*4);  float* i4 = (float*)alloc(524288u*4);
  unsigned short* z1  = (unsigned short*)alloc(2097152u*2);   // full-res spikes L1
  unsigned short* z2p = (unsigned short*)alloc(1048576u*2);   // pooled L2: [32][16][16][128]
  unsigned short* z3p = (unsigned short*)alloc(524288u*2);    // pooled L3: [32][8][8][256]
  float* p0 = (float*)alloc(524288u*4);  // conv4 half-K partial (kh=0)
  float* p1 = (float*)alloc(524288u*4);  // conv4 half-K partial (kh=1)
  float* vl = (float*)alloc(1280);
  float* il = (float*)alloc(1280);
  unsigned short* wb2h = (unsigned short*)alloc(73728u*2);
  unsigned short* wb2m = (unsigned short*)alloc(73728u*2);
  unsigned short* wb2l = (unsigned short*)alloc(73728u*2);
  unsigned short* wb3h = (unsigned short*)alloc(294912u*2);
  unsigned short* wb3m = (unsigned short*)alloc(294912u*2);
  unsigned short* wb3l = (unsigned short*)alloc(294912u*2);
  unsigned short* wb4h = (unsigned short*)alloc(589824u*2);
  unsigned short* wb4m = (unsigned short*)alloc(589824u*2);
  unsigned short* wb4l = (unsigned short*)alloc(589824u*2);

  prep_kernel<<<3744, 256, 0, stream>>>(w2, w3, w4,
      wb2h, wb2m, wb2l, wb3h, wb3m, wb3l, wb4h, wb4m, wb4l);

  for (int t = 0; t < 16; t++) {
    k1_conv1_lif<<<512, 256, 0, stream>>>(x, w1, v1, i1, z1, t);
    // conv2: 64->128 @32x32, BM=64 BN=64 NT=2, grid 1024
    conv_lif<4, 64,32,32,128, 64,2,false,true><<<1024, 256, 0, stream>>>(
        z1, wb2h, wb2m, wb2l, v2, i2, z2p, nullptr, nullptr, t);
    // conv3: 128->256 @16x16 pooled-in, BM=32 BN=64 NT=4, grid 1024
    conv_lif<2,128,16,16,256,128,4,false,true><<<1024, 256, 0, stream>>>(
        z2p, wb3h, wb3m, wb3l, v3, i3, z3p, nullptr, nullptr, t);
    // conv4: 256->256 @8x8 pooled-in, K-split 2 via separate partials, grid 512
    conv_lif<2,128, 8, 8,256,256,4,true,false><<<512, 256, 0, stream>>>(
        z3p, wb4h, wb4m, wb4l, nullptr, nullptr, nullptr, p0, p1, t);
    k5_lif4_fc<<<32, 512, 0, stream>>>(p0, p1, v4, i4, wfc, noise, vl, il, dout, t);
  }
}